// Round 3
// baseline (459.656 us; speedup 1.0000x reference)
//
#include <hip/hip_runtime.h>

// LSTM cell: fp32 inputs, fp32 output (bf16-lenient compare).
// gates[B,3H] = x@Wx^T + h@Wh^T + b; new_c = sig(gf)*c + sig(gi)*tanh(gg).
// M=16384, N=1024 x 3 gates, K=2048 (x||h fused).
//
// v4: A-in-registers + B-only LDS ring. Round-2 was LDS-BW-bound:
// (DMA-writes + reads) = 60KB per 96-MFMA phase -> 41% ceiling (measured 43%).
// Now: A fragments load straight to VGPRs from a fragment-ordered ws
// (wave-private data never touches LDS); only B (4-wave-shared) streams
// through LDS via global_load_lds ring-4. LDS/MFMA: 0.625KB -> 82% ceiling.
//  - block 256M x 32N x 3gates, 4 waves, wave = 64M(distinct) x 32N x 3g
//  - phase K=64: 8 A-reg loads + 3 B-DMA + 12 ds_read_b128 + 24 MFMA / wave
//  - counted vmcnt: steady-state WAITVM(14) = DMA(h+1,h+2)[6] + A(h)[8]
//  - A ws: [m32t:512][k32t:64][ks:2][lane:64][16B]  (64 MB)
//  - W ws: [nt:32][k64t:32][frag12=g*4+ks][lane:64][16B]  (12 MB)

#define HS 1024

typedef __bf16 bf16;
typedef bf16  bf16x4  __attribute__((ext_vector_type(4)));
typedef bf16  bf16x8  __attribute__((ext_vector_type(8)));
typedef float f32x4   __attribute__((ext_vector_type(4)));
typedef float f32x16  __attribute__((ext_vector_type(16)));

#define WAITVM(N) asm volatile("s_waitcnt vmcnt(" #N ")" ::: "memory")

__device__ __forceinline__ void cp16(void* lds, const void* g) {
  __builtin_amdgcn_global_load_lds(
      (const __attribute__((address_space(1))) void*)g,
      (__attribute__((address_space(3))) void*)lds, 16, 0, 0);
}

// ---------------------------------------------------------------------------
// pack_a: x||h -> bf16 fragment-ordered ws. Thread = (row r, 32-col group cg).
// Reads 8 x f32x4 from one row (each lane consumes its own full 128B lines);
// writes 4 x 16B chunks (L2 merges partial lines).
__global__ __launch_bounds__(256) void pack_a(const float* __restrict__ x,
                                              const float* __restrict__ h,
                                              bf16* __restrict__ Aws) {
  const unsigned T  = blockIdx.x * 256 + threadIdx.x;   // 1,048,576 threads
  const unsigned r  = T >> 6;          // row 0..16383
  const unsigned cg = T & 63u;         // k32-tile 0..63
  const float* src = (cg < 32u) ? (x + (size_t)r * HS + cg * 32u)
                                : (h + (size_t)r * HS + (cg - 32u) * 32u);
  float v[32];
#pragma unroll
  for (int c = 0; c < 8; ++c) {
    const f32x4 t = *(const f32x4*)(src + c * 4);
    v[c*4+0] = t[0]; v[c*4+1] = t[1]; v[c*4+2] = t[2]; v[c*4+3] = t[3];
  }
  const unsigned m32t = r >> 5, lane_m = r & 31u;
  char* obase = (char*)Aws + (size_t)m32t * 131072u + cg * 2048u;
#pragma unroll
  for (int ks = 0; ks < 2; ++ks)
#pragma unroll
    for (int hi = 0; hi < 2; ++hi) {
      bf16x8 o;
#pragma unroll
      for (int j = 0; j < 8; ++j) o[j] = (bf16)v[ks*16 + hi*8 + j];
      *(bf16x8*)(obase + ks*1024 + (hi*32 + (int)lane_m)*16) = o;
    }
}

// pack_w: 6 weights -> bf16 DMA-image ws [nt][k64t][g*4+ks][lane][16B].
__global__ __launch_bounds__(256) void pack_w(
    const float* __restrict__ w_ii, const float* __restrict__ w_hi,
    const float* __restrict__ w_if, const float* __restrict__ w_hf,
    const float* __restrict__ w_ig, const float* __restrict__ w_hg,
    bf16* __restrict__ Wws) {
  const unsigned T  = blockIdx.x * 256 + threadIdx.x;   // 196,608 threads
  const unsigned g  = T >> 16;         // gate 0..2
  const unsigned Tr = T & 65535u;
  const unsigned r  = Tr >> 6;         // row n 0..1023
  const unsigned cg = Tr & 63u;        // 32-col group
  const float* wx = (g == 0) ? w_ii : (g == 1) ? w_if : w_ig;
  const float* wh = (g == 0) ? w_hi : (g == 1) ? w_hf : w_hg;
  const float* src = (cg < 32u) ? (wx + (size_t)r * HS + cg * 32u)
                                : (wh + (size_t)r * HS + (cg - 32u) * 32u);
  float v[32];
#pragma unroll
  for (int c = 0; c < 8; ++c) {
    const f32x4 t = *(const f32x4*)(src + c * 4);
    v[c*4+0] = t[0]; v[c*4+1] = t[1]; v[c*4+2] = t[2]; v[c*4+3] = t[3];
  }
  const unsigned nt32 = r >> 5, lane_m = r & 31u;
  const unsigned k64t = cg >> 1, khalf = cg & 1u;
  char* obase = (char*)Wws + (size_t)nt32 * 393216u + (size_t)k64t * 12288u
              + g * 4096u + khalf * 2048u;
#pragma unroll
  for (int ks = 0; ks < 2; ++ks)       // ks within the k32-half
#pragma unroll
    for (int hi = 0; hi < 2; ++hi) {
      bf16x8 o;
#pragma unroll
      for (int j = 0; j < 8; ++j) o[j] = (bf16)v[ks*16 + hi*8 + j];
      *(bf16x8*)(obase + ks*1024 + (hi*32 + (int)lane_m)*16) = o;
    }
}

// ---------------------------------------------------------------------------
// GEMM: block = 256M x 32N x 3 gates, 4 waves; wave = 64M x 32N x 3g.
// A from registers, B via LDS ring-4 (K=64 tiles, 12KB each).
__global__ __launch_bounds__(256, 2) void lstm_gemm(
    const bf16* __restrict__ Aws, const bf16* __restrict__ Wws,
    const float* __restrict__ c,
    const float* __restrict__ b_ii, const float* __restrict__ b_hi,
    const float* __restrict__ b_if, const float* __restrict__ b_hf,
    const float* __restrict__ b_ig, const float* __restrict__ b_hg,
    float* __restrict__ out)
{
  __shared__ __align__(16) char smem[4 * 12288];   // 48 KB

  const int tid  = threadIdx.x;
  const int lane = tid & 63;
  const int wave = tid >> 6;

  // XCD-bijective swizzle: 2048 wgs = 8 XCD x 256. nt-minor: the 64 blocks
  // co-resident per XCD span 2 mt x 32 nt -> A working set 2MB fits 4MB L2.
  const int bid = blockIdx.x;
  const int wg  = (bid & 7) * 256 + (bid >> 3);
  const int nt  = wg & 31;
  const int mt  = wg >> 5;
  const int m0  = mt * 256;
  const int n0  = nt * 32;
  const int lb  = lane * 16;

  const char* Apan0 = (const char*)Aws + (size_t)(mt * 8 + wave * 2) * 131072u + lb;
  const char* Apan1 = Apan0 + 131072;
  const char* Wpan  = (const char*)Wws + (size_t)nt * 393216u;

  f32x16 acc[3][2] = {};

  // stage B K64-tile t into ring slot t&3 (3 x 1KB per wave, uniform)
  auto stageB = [&](int t) {
    char* dst = smem + (t & 3) * 12288 + wave * 3072;
    const char* src = Wpan + (size_t)t * 12288u + wave * 3072 + lb;
    cp16(dst,        src);
    cp16(dst + 1024, src + 1024);
    cp16(dst + 2048, src + 2048);
  };

  bf16x8 aA[2][4], aB[2][4];
  auto loadA = [&](int t, bf16x8 (&d)[2][4]) {
#pragma unroll
    for (int j = 0; j < 4; ++j) {
      d[0][j] = *(const bf16x8*)(Apan0 + t * 4096 + j * 1024);
      d[1][j] = *(const bf16x8*)(Apan1 + t * 4096 + j * 1024);
    }
  };

  auto compute = [&](int t, bf16x8 (&a)[2][4]) {
    const char* bufB = smem + (t & 3) * 12288 + lb;
#pragma unroll
    for (int ks = 0; ks < 4; ++ks) {
      const bf16x8 b0 = *(const bf16x8*)(bufB + (0 * 4 + ks) * 1024);
      const bf16x8 b1 = *(const bf16x8*)(bufB + (1 * 4 + ks) * 1024);
      const bf16x8 b2 = *(const bf16x8*)(bufB + (2 * 4 + ks) * 1024);
      __builtin_amdgcn_s_setprio(1);
      acc[0][0] = __builtin_amdgcn_mfma_f32_32x32x16_bf16(a[0][ks], b0, acc[0][0], 0, 0, 0);
      acc[0][1] = __builtin_amdgcn_mfma_f32_32x32x16_bf16(a[1][ks], b0, acc[0][1], 0, 0, 0);
      acc[1][0] = __builtin_amdgcn_mfma_f32_32x32x16_bf16(a[0][ks], b1, acc[1][0], 0, 0, 0);
      acc[1][1] = __builtin_amdgcn_mfma_f32_32x32x16_bf16(a[1][ks], b1, acc[1][1], 0, 0, 0);
      acc[2][0] = __builtin_amdgcn_mfma_f32_32x32x16_bf16(a[0][ks], b2, acc[2][0], 0, 0, 0);
      acc[2][1] = __builtin_amdgcn_mfma_f32_32x32x16_bf16(a[1][ks], b2, acc[2][1], 0, 0, 0);
      __builtin_amdgcn_s_setprio(0);
    }
  };

  // prologue: 3 B-tiles in flight + A(0) in regs
  stageB(0); stageB(1); stageB(2);
  loadA(0, aA);

  // Per phase t: wait {DMA(t) done} -> barrier -> issue A(t+1), B-DMA(t+3)
  // -> ds_read B(t) + 24 MFMA. vmcnt never drains below 8 mid-loop.
  // Steady outstanding at wait: DMA(t+1)3 + DMA(t+2)3 + A(t)8 = 14.
#define PHASE(T_, CUR_, NXT_)                                          \
  {                                                                    \
    const int t_ = (T_);                                               \
    if (t_ < 30)      { WAITVM(14); }                                  \
    else if (t_ == 30){ WAITVM(11); }                                  \
    else              { WAITVM(8);  }                                  \
    asm volatile("s_waitcnt lgkmcnt(0)" ::: "memory");                 \
    __builtin_amdgcn_s_barrier();                                      \
    if (t_ < 31) loadA(t_ + 1, NXT_);                                  \
    if (t_ < 29) stageB(t_ + 3);                                       \
    compute(t_, CUR_);                                                 \
  }

  for (int hh = 0; hh < 32; hh += 2) {
    PHASE(hh,     aA, aB)
    PHASE(hh + 1, aB, aA)
  }
#undef PHASE

  // Epilogue. C/D 32x32 layout: col n = lane&31, row = (r&3)+8*(r>>2)+4*(lane>>5).
  const int n  = n0 + (lane & 31);
  const int rb = (lane >> 5) * 4;
  const float bi  = b_ii[n] + b_hi[n];
  const float bf_ = b_if[n] + b_hf[n];
  const float bg  = b_ig[n] + b_hg[n];
#pragma unroll
  for (int i = 0; i < 2; ++i) {
#pragma unroll
    for (int r = 0; r < 16; ++r) {
      const int m = m0 + wave * 64 + i * 32 + (r & 3) + 8 * (r >> 2) + rb;
      const size_t idx = (size_t)m * HS + n;
      const float gi = acc[0][i][r] + bi;
      const float gf = acc[1][i][r] + bf_;
      const float gg = acc[2][i][r] + bg;
      const float it = 1.f / (1.f + __expf(-gi));
      const float ft = 1.f / (1.f + __expf(-gf));
      const float e2 = __expf(-2.f * gg);
      const float gt = (1.f - e2) / (1.f + e2);  // tanh
      out[idx] = ft * c[idx] + it * gt;
    }
  }
}

// ===========================================================================
// Legacy fallback — used only if workspace too small.
#define K_TOTAL 2048
#define BK      32
#define NITER   (K_TOTAL / BK)

__device__ __forceinline__ void ldpanel(const float* __restrict__ src, int tid,
                                        f32x4* __restrict__ v) {
#pragma unroll
  for (int b = 0; b < 2; ++b) {
    const int cc  = tid + b * 256;
    const int row = cc >> 3;
    const int col = (cc & 7) * 4;
    v[b] = *(const f32x4*)(src + (size_t)row * HS + col);
  }
}

__device__ __forceinline__ void stpanel(bf16* __restrict__ dst, int tid,
                                        const f32x4* __restrict__ v) {
#pragma unroll
  for (int b = 0; b < 2; ++b) {
    const int cc  = tid + b * 256;
    const int row = cc >> 3;
    const int col = (cc & 7) * 4;
    bf16x4 o;
    o[0] = (bf16)v[b][0]; o[1] = (bf16)v[b][1];
    o[2] = (bf16)v[b][2]; o[3] = (bf16)v[b][3];
    *(bf16x4*)(dst + row * 32 + col) = o;
  }
}

__device__ __forceinline__ void get_srcs(
    int k, int m0, int n0,
    const float* __restrict__ x, const float* __restrict__ h,
    const float* __restrict__ w_ii, const float* __restrict__ w_hi,
    const float* __restrict__ w_if, const float* __restrict__ w_hf,
    const float* __restrict__ w_ig, const float* __restrict__ w_hg,
    const float* s[5]) {
  const int kk = k * BK;
  const float* Ag; const float* w0; const float* w1; const float* w2; int kl;
  if (kk < 1024) { Ag = x; w0 = w_ii; w1 = w_if; w2 = w_ig; kl = kk; }
  else           { Ag = h; w0 = w_hi; w1 = w_hf; w2 = w_hg; kl = kk - 1024; }
  s[0] = Ag + (size_t)m0 * HS + kl;
  s[1] = Ag + (size_t)(m0 + 64) * HS + kl;
  s[2] = w0 + (size_t)n0 * HS + kl;
  s[3] = w1 + (size_t)n0 * HS + kl;
  s[4] = w2 + (size_t)n0 * HS + kl;
}

__global__ __launch_bounds__(256, 2) void lstm_fused(
    const float* __restrict__ x, const float* __restrict__ h,
    const float* __restrict__ c,
    const float* __restrict__ w_ii, const float* __restrict__ w_hi,
    const float* __restrict__ w_if, const float* __restrict__ w_hf,
    const float* __restrict__ w_ig, const float* __restrict__ w_hg,
    const float* __restrict__ b_ii, const float* __restrict__ b_hi,
    const float* __restrict__ b_if, const float* __restrict__ b_hf,
    const float* __restrict__ b_ig, const float* __restrict__ b_hg,
    float* __restrict__ out)
{
  __shared__ bf16 smem[2 * 10240];

  const int tid  = threadIdx.x;
  const int lane = tid & 63;
  const int wave = tid >> 6;

  const int bid = blockIdx.x;
  const int nt  = bid & 15;
  const int mt  = bid >> 4;
  const int m0  = mt * 128;
  const int n0  = nt * 64;
  const int wm  = (wave & 1) * 64;
  const int wn  = (wave >> 1) * 32;

  f32x16 acc[3][2] = {};

  {
    const float* s[5];
    get_srcs(0, m0, n0, x, h, w_ii, w_hi, w_if, w_hf, w_ig, w_hg, s);
    f32x4 pf[5][2];
#pragma unroll
    for (int p = 0; p < 5; ++p) ldpanel(s[p], tid, pf[p]);
    bf16* A0 = smem;
#pragma unroll
    for (int p = 0; p < 5; ++p) stpanel(A0 + p * 2048, tid, pf[p]);
    __syncthreads();
  }

  const int fr  = lane & 31;
  const int fk8 = (lane >> 5) * 8;

  for (int k = 0; k < NITER; ++k) {
    bf16* As = smem + (k & 1) * 10240;
    bf16* Bs = As + 4096;

    f32x4 nf[5][2];
    if (k < NITER - 1) {
      const float* s[5];
      get_srcs(k + 1, m0, n0, x, h, w_ii, w_hi, w_if, w_hf, w_ig, w_hg, s);
#pragma unroll
      for (int p = 0; p < 5; ++p) ldpanel(s[p], tid, nf[p]);
    }

#pragma unroll
    for (int ks = 0; ks < 2; ++ks) {
      const int co = ks * 16 + fk8;
      bf16x8 a0 = *(const bf16x8*)(As + (wm + fr) * 32 + co);
      bf16x8 a1 = *(const bf16x8*)(As + (wm + 32 + fr) * 32 + co);
#pragma unroll
      for (int g = 0; g < 3; ++g) {
        bf16x8 b = *(const bf16x8*)(Bs + g * 2048 + (wn + fr) * 32 + co);
        acc[g][0] = __builtin_amdgcn_mfma_f32_32x32x16_bf16(a0, b, acc[g][0], 0, 0, 0);
        acc[g][1] = __builtin_amdgcn_mfma_f32_32x32x16_bf16(a1, b, acc[g][1], 0, 0, 0);
      }
    }

    if (k < NITER - 1) {
      bf16* An = smem + ((k + 1) & 1) * 10240;
#pragma unroll
      for (int p = 0; p < 5; ++p) stpanel(An + p * 2048, tid, nf[p]);
    }
    __syncthreads();
  }

  const int n   = n0 + wn + (lane & 31);
  const int rb  = (lane >> 5) * 4;
  const float bi  = b_ii[n] + b_hi[n];
  const float bf_ = b_if[n] + b_hf[n];
  const float bg  = b_ig[n] + b_hg[n];
#pragma unroll
  for (int i = 0; i < 2; ++i) {
#pragma unroll
    for (int r = 0; r < 16; ++r) {
      const int m = m0 + wm + i * 32 + (r & 3) + 8 * (r >> 2) + rb;
      const size_t idx = (size_t)m * HS + n;
      const float gi = acc[0][i][r] + bi;
      const float gf = acc[1][i][r] + bf_;
      const float gg = acc[2][i][r] + bg;
      const float it = 1.f / (1.f + __expf(-gi));
      const float ft = 1.f / (1.f + __expf(-gf));
      const float e2 = __expf(-2.f * gg);
      const float gt = (1.f - e2) / (1.f + e2);
      out[idx] = ft * c[idx] + it * gt;
    }
  }
}

// ===========================================================================
extern "C" void kernel_launch(void* const* d_in, const int* in_sizes, int n_in,
                              void* d_out, int out_size, void* d_ws, size_t ws_size,
                              hipStream_t stream) {
  const float* x  = (const float*)d_in[0];
  const float* h  = (const float*)d_in[1];
  const float* c  = (const float*)d_in[2];
  const float* w_ii = (const float*)d_in[3];
  const float* b_ii = (const float*)d_in[4];
  const float* w_hi = (const float*)d_in[5];
  const float* b_hi = (const float*)d_in[6];
  const float* w_if = (const float*)d_in[7];
  const float* b_if = (const float*)d_in[8];
  const float* w_hf = (const float*)d_in[9];
  const float* b_hf = (const float*)d_in[10];
  const float* w_ig = (const float*)d_in[11];
  const float* b_ig = (const float*)d_in[12];
  const float* w_hg = (const float*)d_in[13];
  const float* b_hg = (const float*)d_in[14];
  float* out = (float*)d_out;

  const size_t needA = (size_t)512 * 131072u;   // 64 MB
  const size_t needW = (size_t)32 * 393216u;    // 12 MB

  if (ws_size >= needA + needW) {
    bf16* Aws = (bf16*)d_ws;
    bf16* Wws = (bf16*)((char*)d_ws + needA);
    hipLaunchKernelGGL(pack_a, dim3(4096), dim3(256), 0, stream, x, h, Aws);
    hipLaunchKernelGGL(pack_w, dim3(768), dim3(256), 0, stream,
                       w_ii, w_hi, w_if, w_hf, w_ig, w_hg, Wws);
    hipLaunchKernelGGL(lstm_gemm, dim3(2048), dim3(256), 0, stream,
                       Aws, Wws, c, b_ii, b_hi, b_if, b_hf, b_ig, b_hg, out);
  } else {
    hipLaunchKernelGGL(lstm_fused, dim3(2048), dim3(256), 0, stream,
                       x, h, c, w_ii, w_hi, w_if, w_hf, w_ig, w_hg,
                       b_ii, b_hi, b_if, b_hf, b_ig, b_hg, out);
  }
}